// Round 8
// baseline (126.677 us; speedup 1.0000x reference)
//
#include <hip/hip_runtime.h>
#include <hip/hip_bf16.h>

// Problem constants: N tokens, D d_model, E experts, H hidden, K top-k
#define NTOK 4096
#define DM   512
#define NE   32
#define HD   128
#define TK   4
#define NRB  1024   // router blocks (4 tokens each)

typedef unsigned short u16;
typedef unsigned int   u32;
typedef u16   u16x4 __attribute__((ext_vector_type(4)));
typedef u16   u16x8 __attribute__((ext_vector_type(8)));
typedef short short8 __attribute__((ext_vector_type(8)));
typedef float f32x4 __attribute__((ext_vector_type(4)));
typedef int   int4v __attribute__((ext_vector_type(4)));

__device__ __forceinline__ u16 f2bf(float f) {
    union { float f; u32 u; } v; v.f = f;
    return (u16)((v.u + 0x7FFFu + ((v.u >> 16) & 1u)) >> 16);   // RNE
}
__device__ __forceinline__ float bf2f(u16 h) {
    union { u32 u; float f; } v; v.u = ((u32)h) << 16; return v.f;
}

// ---------------- fused prep (EXACT R4: best measured config) ----------------
// blocks [0,1024):     router, 4 tokens/block; deterministic per-(block,expert) slots:
//                      tok_list[e][bl][0..3], blk_cnt[e][bl] written UNCONDITIONALLY
//                      (no zero-init needed -> no memset node, no atomics).
// blocks [1024,2048):  weight swizzle fp32 -> bf16 fragment-major
__global__ __launch_bounds__(256) void prep_kernel(const float* __restrict__ x,
                                                   const float* __restrict__ sel,
                                                   const float* __restrict__ w1,
                                                   const float* __restrict__ w2,
                                                   int* __restrict__ blk_cnt,
                                                   int* __restrict__ tok_list,
                                                   float* __restrict__ gate_list,
                                                   u16* __restrict__ xbf,
                                                   u16* __restrict__ wf1,
                                                   u16* __restrict__ wf2) {
    __shared__ float  xs[4][520];
    __shared__ double sc[4][33];
    __shared__ int    pk_e[16];
    __shared__ float  pk_g[16];
    int tid = threadIdx.x;
    int wv = tid >> 6, lane = tid & 63;

    if (blockIdx.x >= NRB) {
        // ---- weight swizzle: 2 fragments per wave ----
        int m = lane & 15, q = lane >> 4;
        int f0 = ((blockIdx.x - NRB) * 4 + wv) * 2;
        const float* in[2]; u16* outp[2]; int Nd[2];
#pragma unroll
        for (int u = 0; u < 2; ++u) {
            int w = f0 + u;
            if (w < 4096) {
                int e = w >> 7, rem = w & 127, ks = rem >> 3, nt = rem & 7;
                in[u] = w1 + (size_t)e * DM * HD + (size_t)(32 * ks + q * 8) * HD + 16 * nt + m;
                Nd[u] = HD;
                outp[u] = wf1 + (size_t)w * 512 + lane * 8;
            } else {
                int wl = w - 4096, e = wl >> 7, rem = wl & 127, ks = rem >> 5, nt = rem & 31;
                in[u] = w2 + (size_t)e * HD * DM + (size_t)(32 * ks + q * 8) * DM + 16 * nt + m;
                Nd[u] = DM;
                outp[u] = wf2 + (size_t)wl * 512 + lane * 8;
            }
        }
        float v[2][8];
#pragma unroll
        for (int u = 0; u < 2; ++u)
#pragma unroll
            for (int j = 0; j < 8; ++j) v[u][j] = in[u][(size_t)j * Nd[u]];
#pragma unroll
        for (int u = 0; u < 2; ++u) {
            u16x8 h;
#pragma unroll
            for (int j = 0; j < 8; ++j) h[j] = f2bf(v[u][j]);
            *(u16x8*)outp[u] = h;
        }
        return;
    }

    // ---- router: 4 tokens/block (verbatim R4 math) ----
    int bl = blockIdx.x;
    int tb = bl * 4;
#pragma unroll
    for (int rep = 0; rep < 2; ++rep) {
        int idx = (rep * 256 + tid) * 4;            // element in 4x512 tile
        int row = idx >> 9, col = idx & 511;
        f32x4 v = *(const f32x4*)(x + (size_t)(tb + row) * DM + col);
        *(f32x4*)&xs[row][col] = v;
        u16x4 h;
#pragma unroll
        for (int j = 0; j < 4; ++j) h[j] = f2bf(v[j]);
        *(u16x4*)(xbf + (size_t)(tb + row) * DM + col) = h;
    }
    __syncthreads();

    // thread: tok = tid&3, seg = (tid>>2)&1, e = tid>>3 ; 256-long fp64 dot, 4 chains
    int tok = tid & 3, seg = (tid >> 2) & 1, e = tid >> 3;
    const float* sp = sel + (size_t)e * DM + seg * 256;
    const float* xp = &xs[tok][seg * 256];
    double pa = 0.0, pb = 0.0, pc = 0.0, pd = 0.0;
#pragma unroll 4
    for (int j = 0; j < 256; j += 16) {
        f32x4 x0 = *(const f32x4*)(xp + j);
        f32x4 x1 = *(const f32x4*)(xp + j + 4);
        f32x4 x2 = *(const f32x4*)(xp + j + 8);
        f32x4 x3 = *(const f32x4*)(xp + j + 12);
        f32x4 s0 = *(const f32x4*)(sp + j);
        f32x4 s1 = *(const f32x4*)(sp + j + 4);
        f32x4 s2 = *(const f32x4*)(sp + j + 8);
        f32x4 s3 = *(const f32x4*)(sp + j + 12);
#pragma unroll
        for (int k = 0; k < 4; ++k) {
            pa = fma((double)x0[k], (double)s0[k], pa);
            pb = fma((double)x1[k], (double)s1[k], pb);
            pc = fma((double)x2[k], (double)s2[k], pc);
            pd = fma((double)x3[k], (double)s3[k], pd);
        }
    }
    double p = (pa + pb) + (pc + pd);
    p += __shfl_xor(p, 4);                          // combine the two K-halves
    if (seg == 0) sc[tok][e] = p;
    __syncthreads();

    // top-k per token -> LDS pick lists (math identical to R4)
    if (tid < 4) {
        unsigned mask = 0;
        for (int k = 0; k < TK; ++k) {
            double best = -1e300; int be = 0;
            for (int ee = 0; ee < NE; ++ee) {
                double v = sc[tid][ee];
                if (!((mask >> ee) & 1u) && v > best) { best = v; be = ee; }
            }
            mask |= 1u << be;
            pk_e[tid * 4 + k] = be;
            pk_g[tid * 4 + k] = 1.0f / (1.0f + __expf(-(float)best));
        }
    }
    __syncthreads();

    // deterministic append: expert tid owns region tok_list[(tid*NRB+bl)*4 ..]
    if (tid < NE) {
        int e2 = tid, cnt = 0;
        int base = (e2 * NRB + bl) * 4;
#pragma unroll
        for (int i = 0; i < 16; ++i) {
            if (pk_e[i] == e2) {
                tok_list[base + cnt]  = ((i & 3) << 16) | (tb + (i >> 2));
                gate_list[base + cnt] = pk_g[i];
                ++cnt;
            }
        }
        blk_cnt[e2 * NRB + bl] = cnt;               // written for EVERY (e,bl)
    }
}

// ---------------- fused expert MLP (R4 + ONLY: 4 blocks/CU via small LDS) ----------------
// Change vs R4 (isolated A/B): __launch_bounds__(256,4) + half-height Ct[16][520]
// two-pass epilogue (LDS 44.5 -> 29.8 KB) -> 4 blocks/CU so L2 weight-load latency
// in the GEMM k-loops is covered by 2x the waves. Everything else verbatim R4.
__global__ __launch_bounds__(256, 4) void moe_mlp_kernel(const u16* __restrict__ xbf,
                                                         const u16* __restrict__ wf1,
                                                         const u16* __restrict__ wf2,
                                                         const int* __restrict__ blk_cnt,
                                                         const int* __restrict__ tok_list,
                                                         const float* __restrict__ gate_list,
                                                         u16* __restrict__ part,
                                                         float* __restrict__ out,
                                                         int use_part) {
    __shared__ int   s_tot[4];
    __shared__ int   s_red[4][4];                   // [wave][expert-slot]
    __shared__ int   s_pref[NRB + 1];               // 4.1 KB
    __shared__ int   s_ent[32];
    __shared__ float s_gate[32];
    __shared__ __align__(16) u16 Hm[32][136];       // 8.7 KB
    __shared__ __align__(16) u16 Ct[16][520];       // 16.6 KB (half-height, 2 passes)

    int tid = threadIdx.x;
    int wv = tid >> 6, lane = tid & 63;
    int xcd = blockIdx.x & 7, idx0 = blockIdx.x >> 3;   // 128 blocks per group

    // ---- per-expert totals for this group's 4 experts ----
    int lsums[4];
#pragma unroll
    for (int j = 0; j < 4; ++j) {
        int4v v = *(const int4v*)&blk_cnt[(size_t)(xcd + 8 * j) * NRB + tid * 4];
        lsums[j] = v[0] + v[1] + v[2] + v[3];
    }
#pragma unroll
    for (int j = 0; j < 4; ++j) {
        int s = lsums[j];
#pragma unroll
        for (int off = 32; off >= 1; off >>= 1) s += __shfl_down(s, off);
        if (lane == 0) s_red[wv][j] = s;
    }
    __syncthreads();
    if (tid < 4) s_tot[tid] = s_red[0][tid] + s_red[1][tid] + s_red[2][tid] + s_red[3][tid];
    __syncthreads();

    int c0 = s_tot[0], c1 = s_tot[1], c2 = s_tot[2], c3 = s_tot[3];
    int n0 = (c0 + 31) >> 5, n1 = (c1 + 31) >> 5, n2 = (c2 + 31) >> 5, n3 = (c3 + 31) >> 5;
    int tot = n0 + n1 + n2 + n3;

    int m = lane & 15, q = lane >> 4;
    int r = wv >> 1, c = wv & 1;                    // GEMM1: rows 16r..+16, cols 64c..+64
    int e_last = -1;

    for (int idx = idx0; idx < tot; idx += 128) {
        int e2, t2, cc;
        if (idx < n0)                { e2 = xcd;      t2 = idx;                cc = c0; }
        else if (idx < n0 + n1)      { e2 = xcd + 8;  t2 = idx - n0;           cc = c1; }
        else if (idx < n0 + n1 + n2) { e2 = xcd + 16; t2 = idx - n0 - n1;      cc = c2; }
        else                         { e2 = xcd + 24; t2 = idx - n0 - n1 - n2; cc = c3; }
        int rows = cc - t2 * 32; if (rows > 32) rows = 32;

        __syncthreads();                            // prev iter's readers done

        if (e2 != e_last) {
            // exclusive prefix scan of blk_cnt[e2][0..NRB) into s_pref
            int4v v = *(const int4v*)&blk_cnt[(size_t)e2 * NRB + tid * 4];
            int lsum = v[0] + v[1] + v[2] + v[3];
            int incl = lsum;
#pragma unroll
            for (int off = 1; off < 64; off <<= 1) {
                int t3 = __shfl_up(incl, off);
                if (lane >= off) incl += t3;
            }
            if (lane == 63) s_red[0][wv] = incl;
            __syncthreads();
            int woff = 0;
#pragma unroll
            for (int w2 = 0; w2 < 4; ++w2) if (w2 < wv) woff += s_red[0][w2];
            int excl = woff + incl - lsum;
            s_pref[tid * 4 + 0] = excl;
            s_pref[tid * 4 + 1] = excl + v[0];
            s_pref[tid * 4 + 2] = excl + v[0] + v[1];
            s_pref[tid * 4 + 3] = excl + v[0] + v[1] + v[2];
            if (tid == 255) s_pref[NRB] = excl + lsum;
            e_last = e2;
            __syncthreads();
        }

        // gather this tile's 32 entries via binary search on s_pref
        if (tid < 32) {
            int row = t2 * 32 + tid;
            bool val = tid < rows;
            int rr = val ? row : 0;
            int lo = 0, hi = NRB;
            while (hi - lo > 1) { int mid = (lo + hi) >> 1; if (s_pref[mid] <= rr) lo = mid; else hi = mid; }
            int sub = rr - s_pref[lo];
            s_ent[tid]  = tok_list[((size_t)e2 * NRB + lo) * 4 + sub];
            s_gate[tid] = val ? gate_list[((size_t)e2 * NRB + lo) * 4 + sub] : 0.0f;
        }
        __syncthreads();

        const u16* w1f = wf1 + (size_t)e2 * (128 * 512);
        const u16* w2f = wf2 + (size_t)e2 * (128 * 512);
        const u16* a0 = xbf + (size_t)(s_ent[16 * r + m] & 0xFFFF) * DM + q * 8;

        // GEMM1: k-steps in pairs, double-buffered
        short8 ab[2][2];
        short8 bb[2][2][4];
#pragma unroll
        for (int kk = 0; kk < 2; ++kk) {
            ab[0][kk] = *(const short8*)(a0 + 32 * kk);
            const u16* bp = w1f + (size_t)kk * 4096 + (size_t)(4 * c) * 512 + lane * 8;
#pragma unroll
            for (int n = 0; n < 4; ++n) bb[0][kk][n] = *(const short8*)(bp + n * 512);
        }
        f32x4 acc[4];
#pragma unroll
        for (int n = 0; n < 4; ++n) acc[n] = (f32x4){0.f, 0.f, 0.f, 0.f};

#pragma unroll
        for (int kp = 0; kp < 8; ++kp) {
            int cur = kp & 1, nxt = cur ^ 1;
            if (kp < 7) {
                int ks0 = 2 * (kp + 1);
#pragma unroll
                for (int kk = 0; kk < 2; ++kk) {
                    ab[nxt][kk] = *(const short8*)(a0 + 32 * (ks0 + kk));
                    const u16* bp = w1f + (size_t)(ks0 + kk) * 4096 + (size_t)(4 * c) * 512 + lane * 8;
#pragma unroll
                    for (int n = 0; n < 4; ++n) bb[nxt][kk][n] = *(const short8*)(bp + n * 512);
                }
            }
#pragma unroll
            for (int kk = 0; kk < 2; ++kk)
#pragma unroll
                for (int n = 0; n < 4; ++n)
                    acc[n] = __builtin_amdgcn_mfma_f32_16x16x32_bf16(ab[cur][kk],
                                                                     bb[cur][kk][n],
                                                                     acc[n], 0, 0, 0);
        }

        // relu * gate -> Hm
        {
            int rb = 16 * r + q * 4;
#pragma unroll
            for (int n = 0; n < 4; ++n)
#pragma unroll
                for (int rr2 = 0; rr2 < 4; ++rr2)
                    Hm[rb + rr2][64 * c + 16 * n + m] =
                        f2bf(fmaxf(acc[n][rr2], 0.f) * s_gate[rb + rr2]);
        }

        // GEMM2: wave owns cols [128*wv, +128); w2 frags double-buffered per k-slice
        short8 cb[2][8];
        {
            const u16* bp = w2f + (size_t)(wv * 8) * 512 + lane * 8;
#pragma unroll
            for (int n = 0; n < 8; ++n) cb[0][n] = *(const short8*)(bp + n * 512);
        }
        __syncthreads();                            // Hm ready

        f32x4 acc2[2][8];
#pragma unroll
        for (int i = 0; i < 2; ++i)
#pragma unroll
            for (int n = 0; n < 8; ++n) acc2[i][n] = (f32x4){0.f, 0.f, 0.f, 0.f};
#pragma unroll
        for (int ks = 0; ks < 4; ++ks) {
            int cur = ks & 1, nxt = cur ^ 1;
            if (ks < 3) {
                const u16* bp = w2f + (size_t)((ks + 1) * 32 + wv * 8) * 512 + lane * 8;
#pragma unroll
                for (int n = 0; n < 8; ++n) cb[nxt][n] = *(const short8*)(bp + n * 512);
            }
            short8 h0 = *(const short8*)&Hm[m][32 * ks + q * 8];
            short8 h1 = *(const short8*)&Hm[16 + m][32 * ks + q * 8];
#pragma unroll
            for (int n = 0; n < 8; ++n) {
                acc2[0][n] = __builtin_amdgcn_mfma_f32_16x16x32_bf16(h0, cb[cur][n], acc2[0][n], 0, 0, 0);
                acc2[1][n] = __builtin_amdgcn_mfma_f32_16x16x32_bf16(h1, cb[cur][n], acc2[1][n], 0, 0, 0);
            }
        }

        // epilogue: 2 passes through half-height Ct (16 rows x 512 cols);
        // part layout [k][t][c] exactly as R4.
#pragma unroll
        for (int i = 0; i < 2; ++i) {
            if (i) __syncthreads();                 // pass-0 readers done before rewrite
            {
                int rb = q * 4;
#pragma unroll
                for (int n = 0; n < 8; ++n)
#pragma unroll
                    for (int rr2 = 0; rr2 < 4; ++rr2)
                        Ct[rb + rr2][128 * wv + 16 * n + m] = f2bf(acc2[i][n][rr2]);
            }
            __syncthreads();                        // Ct pass complete
#pragma unroll
            for (int rep = 0; rep < 4; ++rep) {
                int rl = rep * 4 + wv;              // 0..15
                int rt = 16 * i + rl;               // tile row 0..31
                u16x8 v = *(const u16x8*)&Ct[rl][lane * 8];
                if (rt < rows) {
                    int en = s_ent[rt];
                    int tk = en & 0xFFFF, sl2 = en >> 16;
                    if (use_part) {
                        *(u16x8*)(part + ((size_t)sl2 * NTOK + tk) * DM + lane * 8) = v;
                    } else {
                        float* op = out + (size_t)tk * DM + lane * 8;
#pragma unroll
                        for (int j = 0; j < 8; ++j) atomicAdd(&op[j], bf2f(v[j]));
                    }
                }
            }
        }
    }
}

// ---------------- combine: out[t][c] = sum_k part[k][t][c] (verbatim R4) ----------------
__global__ __launch_bounds__(256) void combine_kernel(const u16* __restrict__ part,
                                                      float* __restrict__ out) {
    size_t off = ((size_t)blockIdx.x * 256 + threadIdx.x) * 8;
    float s[8] = {0, 0, 0, 0, 0, 0, 0, 0};
#pragma unroll
    for (int k = 0; k < TK; ++k) {
        u16x8 p = *(const u16x8*)(part + (size_t)k * NTOK * DM + off);
#pragma unroll
        for (int j = 0; j < 8; ++j) s[j] += bf2f(p[j]);
    }
    *(f32x4*)(out + off)     = (f32x4){s[0], s[1], s[2], s[3]};
    *(f32x4*)(out + off + 4) = (f32x4){s[4], s[5], s[6], s[7]};
}

extern "C" void kernel_launch(void* const* d_in, const int* in_sizes, int n_in,
                              void* d_out, int out_size, void* d_ws, size_t ws_size,
                              hipStream_t stream) {
    (void)in_sizes; (void)n_in; (void)out_size;
    const float* x   = (const float*)d_in[0];   // [N, D]
    const float* sel = (const float*)d_in[1];   // [E, D]
    const float* w1  = (const float*)d_in[2];   // [E, D, H]
    const float* w2  = (const float*)d_in[3];   // [E, H, D]
    float* out = (float*)d_out;                 // [N, D]

    char* ws = (char*)d_ws;
    int*   blk_cnt   = (int*)(ws);                                   // 128 KB
    int*   tok_list  = (int*)(ws + (size_t)NE * NRB * 4);            // 512 KB
    float* gate_list = (float*)(ws + (size_t)NE * NRB * 4 * 5);      // 512 KB
    u16*   xbf  = (u16*)(ws + (size_t)NE * NRB * 4 * 9);             // 4 MB
    u16*   wf1  = xbf + (size_t)NTOK * DM;                           // 4 MB
    u16*   wf2  = wf1 + (size_t)NE * HD * DM;                        // 4 MB
    u16*   part = wf2 + (size_t)NE * HD * DM;                        // 16.8 MB

    size_t need = (size_t)NE * NRB * 4 * 9 + (size_t)NTOK * DM * 2
                + 2 * (size_t)NE * HD * DM * 2 + (size_t)TK * NTOK * DM * 2;
    int use_part = (ws_size >= need) ? 1 : 0;

    if (!use_part)
        hipMemsetAsync(d_out, 0, (size_t)NTOK * DM * sizeof(float), stream);

    // blocks [0,1024) router; [1024,2048) swizzle. No memset node.
    prep_kernel<<<2048, 256, 0, stream>>>(x, sel, w1, w2, blk_cnt, tok_list,
                                          gate_list, xbf, wf1, wf2);
    // 8 XCD groups x 128 blocks, internal tile loop; 4 blocks/CU
    moe_mlp_kernel<<<1024, 256, 0, stream>>>(xbf, wf1, wf2, blk_cnt, tok_list,
                                             gate_list, part, out, use_part);
    if (use_part)
        combine_kernel<<<NTOK * DM / 8 / 256, 256, 0, stream>>>(part, out);
}

// Round 9
// 114.823 us; speedup vs baseline: 1.1032x; 1.1032x over previous
//
#include <hip/hip_runtime.h>
#include <hip/hip_bf16.h>

// Problem constants: N tokens, D d_model, E experts, H hidden, K top-k
#define NTOK 4096
#define DM   512
#define NE   32
#define HD   128
#define TK   4
#define NRB  1024   // router blocks (4 tokens each)

typedef unsigned short u16;
typedef unsigned int   u32;
typedef u16   u16x4 __attribute__((ext_vector_type(4)));
typedef u16   u16x8 __attribute__((ext_vector_type(8)));
typedef short short8 __attribute__((ext_vector_type(8)));
typedef float f32x4 __attribute__((ext_vector_type(4)));
typedef int   int4v __attribute__((ext_vector_type(4)));

__device__ __forceinline__ u16 f2bf(float f) {
    union { float f; u32 u; } v; v.f = f;
    return (u16)((v.u + 0x7FFFu + ((v.u >> 16) & 1u)) >> 16);   // RNE
}
__device__ __forceinline__ float bf2f(u16 h) {
    union { u32 u; float f; } v; v.u = ((u32)h) << 16; return v.f;
}

// ---------------- fused prep (R4 router; coalesced LDS-transpose swizzle) ----------------
// blocks [0,1024):     router, 4 tokens/block (verbatim R4 math + slotting)
// blocks [1024,2048):  weight swizzle. NEW: block loads one 32x128 f32 tile fully
//   coalesced (f32x4), XOR-swizzled into LDS (col ^ 16*(row>>3) -> conflict-free
//   read-back at 2 lanes/bank), then emits 8 bf16 fragments. Replaces 16 strided
//   scalar loads/thread with 4 coalesced vector loads/thread.
//   LDS is a union (16.4 KB) so router occupancy is unchanged (R3 lesson).
__global__ __launch_bounds__(256) void prep_kernel(const float* __restrict__ x,
                                                   const float* __restrict__ sel,
                                                   const float* __restrict__ w1,
                                                   const float* __restrict__ w2,
                                                   int* __restrict__ blk_cnt,
                                                   int* __restrict__ tok_list,
                                                   float* __restrict__ gate_list,
                                                   u16* __restrict__ xbf,
                                                   u16* __restrict__ wf1,
                                                   u16* __restrict__ wf2) {
    // union: router { xs 8320B @0, sc 1056B @8320, pk_e 64B @9376, pk_g 64B @9440 }
    //        swizzle { ts 32x128 f32 = 16384B @0 }
    __shared__ __align__(16) char smem[16384];
    int tid = threadIdx.x;
    int wv = tid >> 6, lane = tid & 63;

    if (blockIdx.x >= NRB) {
        // ---- coalesced weight swizzle: 1 tile (8 fragments) per block ----
        float (*ts)[128] = (float(*)[128])smem;
        int s = blockIdx.x - NRB;                   // 0..1023
        const float* base; u16* dst; int nd;
        if (s < 512) {                              // w1 group: e = s>>4, ks = s&15
            int e = s >> 4, ks = s & 15;
            base = w1 + (size_t)e * DM * HD + (size_t)(32 * ks) * HD;
            nd = HD;
            dst = wf1 + (size_t)s * 8 * 512;
        } else {                                    // w2 group
            int G2 = s - 512;
            int e = G2 >> 4, ks2 = (G2 >> 2) & 3, sub = G2 & 3;
            base = w2 + (size_t)e * HD * DM + (size_t)(32 * ks2) * DM + 128 * sub;
            nd = DM;
            dst = wf2 + (size_t)G2 * 8 * 512;
        }
        // load 32x128 tile, coalesced; XOR-swizzle columns per 8-row group
#pragma unroll
        for (int rep = 0; rep < 4; ++rep) {
            int idx = rep * 1024 + tid * 4;
            int row = idx >> 7, col = idx & 127;
            f32x4 v = *(const f32x4*)(base + (size_t)row * nd + col);
            *(f32x4*)&ts[row][col ^ (16 * (row >> 3))] = v;
        }
        __syncthreads();
        // emit 2 fragments per wave: ntp = 2*wv + u; frag[j] = tile[q*8+j][16*ntp+m]
        int m = lane & 15, q = lane >> 4;
#pragma unroll
        for (int u = 0; u < 2; ++u) {
            int ntp = 2 * wv + u;
            u16x8 h;
#pragma unroll
            for (int j = 0; j < 8; ++j)
                h[j] = f2bf(ts[q * 8 + j][(16 * ntp + m) ^ (16 * q)]);
            *(u16x8*)(dst + (size_t)ntp * 512 + lane * 8) = h;
        }
        return;
    }

    float  (*xs)[520] = (float(*)[520])smem;
    double (*sc)[33]  = (double(*)[33])(smem + 8320);
    int*    pk_e      = (int*)(smem + 9376);
    float*  pk_g      = (float*)(smem + 9440);

    // ---- router: 4 tokens/block (verbatim R4 math) ----
    int bl = blockIdx.x;
    int tb = bl * 4;
#pragma unroll
    for (int rep = 0; rep < 2; ++rep) {
        int idx = (rep * 256 + tid) * 4;            // element in 4x512 tile
        int row = idx >> 9, col = idx & 511;
        f32x4 v = *(const f32x4*)(x + (size_t)(tb + row) * DM + col);
        *(f32x4*)&xs[row][col] = v;
        u16x4 h;
#pragma unroll
        for (int j = 0; j < 4; ++j) h[j] = f2bf(v[j]);
        *(u16x4*)(xbf + (size_t)(tb + row) * DM + col) = h;
    }
    __syncthreads();

    // thread: tok = tid&3, seg = (tid>>2)&1, e = tid>>3 ; 256-long fp64 dot, 4 chains
    int tok = tid & 3, seg = (tid >> 2) & 1, e = tid >> 3;
    const float* sp = sel + (size_t)e * DM + seg * 256;
    const float* xp = &xs[tok][seg * 256];
    double pa = 0.0, pb = 0.0, pc = 0.0, pd = 0.0;
#pragma unroll 4
    for (int j = 0; j < 256; j += 16) {
        f32x4 x0 = *(const f32x4*)(xp + j);
        f32x4 x1 = *(const f32x4*)(xp + j + 4);
        f32x4 x2 = *(const f32x4*)(xp + j + 8);
        f32x4 x3 = *(const f32x4*)(xp + j + 12);
        f32x4 s0 = *(const f32x4*)(sp + j);
        f32x4 s1 = *(const f32x4*)(sp + j + 4);
        f32x4 s2 = *(const f32x4*)(sp + j + 8);
        f32x4 s3 = *(const f32x4*)(sp + j + 12);
#pragma unroll
        for (int k = 0; k < 4; ++k) {
            pa = fma((double)x0[k], (double)s0[k], pa);
            pb = fma((double)x1[k], (double)s1[k], pb);
            pc = fma((double)x2[k], (double)s2[k], pc);
            pd = fma((double)x3[k], (double)s3[k], pd);
        }
    }
    double p = (pa + pb) + (pc + pd);
    p += __shfl_xor(p, 4);                          // combine the two K-halves
    if (seg == 0) sc[tok][e] = p;
    __syncthreads();

    // top-k per token -> LDS pick lists (math identical to R4)
    if (tid < 4) {
        unsigned mask = 0;
        for (int k = 0; k < TK; ++k) {
            double best = -1e300; int be = 0;
            for (int ee = 0; ee < NE; ++ee) {
                double v = sc[tid][ee];
                if (!((mask >> ee) & 1u) && v > best) { best = v; be = ee; }
            }
            mask |= 1u << be;
            pk_e[tid * 4 + k] = be;
            pk_g[tid * 4 + k] = 1.0f / (1.0f + __expf(-(float)best));
        }
    }
    __syncthreads();

    // deterministic append: expert tid owns region tok_list[(tid*NRB+bl)*4 ..]
    if (tid < NE) {
        int e2 = tid, cnt = 0;
        int base = (e2 * NRB + bl) * 4;
#pragma unroll
        for (int i = 0; i < 16; ++i) {
            if (pk_e[i] == e2) {
                tok_list[base + cnt]  = ((i & 3) << 16) | (tb + (i >> 2));
                gate_list[base + cnt] = pk_g[i];
                ++cnt;
            }
        }
        blk_cnt[e2 * NRB + bl] = cnt;               // written for EVERY (e,bl)
    }
}

// ---------------- fused expert MLP (verbatim R4: best measured) ----------------
__global__ __launch_bounds__(256, 2) void moe_mlp_kernel(const u16* __restrict__ xbf,
                                                         const u16* __restrict__ wf1,
                                                         const u16* __restrict__ wf2,
                                                         const int* __restrict__ blk_cnt,
                                                         const int* __restrict__ tok_list,
                                                         const float* __restrict__ gate_list,
                                                         u16* __restrict__ part,
                                                         float* __restrict__ out,
                                                         int use_part) {
    __shared__ int   s_tot[4];
    __shared__ int   s_red[4][4];                   // [wave][expert-slot]
    __shared__ int   s_pref[NRB + 1];               // 4.1 KB
    __shared__ int   s_ent[32];
    __shared__ float s_gate[32];
    __shared__ __align__(16) u16 Hm[32][136];       // 272B stride
    __shared__ __align__(16) u16 Ct[32][520];       // 1040B stride

    int tid = threadIdx.x;
    int wv = tid >> 6, lane = tid & 63;
    int xcd = blockIdx.x & 7, idx0 = blockIdx.x >> 3;   // 128 blocks per group

    // ---- per-expert totals for this group's 4 experts ----
    int lsums[4];
#pragma unroll
    for (int j = 0; j < 4; ++j) {
        int4v v = *(const int4v*)&blk_cnt[(size_t)(xcd + 8 * j) * NRB + tid * 4];
        lsums[j] = v[0] + v[1] + v[2] + v[3];
    }
#pragma unroll
    for (int j = 0; j < 4; ++j) {
        int s = lsums[j];
#pragma unroll
        for (int off = 32; off >= 1; off >>= 1) s += __shfl_down(s, off);
        if (lane == 0) s_red[wv][j] = s;
    }
    __syncthreads();
    if (tid < 4) s_tot[tid] = s_red[0][tid] + s_red[1][tid] + s_red[2][tid] + s_red[3][tid];
    __syncthreads();

    int c0 = s_tot[0], c1 = s_tot[1], c2 = s_tot[2], c3 = s_tot[3];
    int n0 = (c0 + 31) >> 5, n1 = (c1 + 31) >> 5, n2 = (c2 + 31) >> 5, n3 = (c3 + 31) >> 5;
    int tot = n0 + n1 + n2 + n3;

    int m = lane & 15, q = lane >> 4;
    int r = wv >> 1, c = wv & 1;                    // GEMM1: rows 16r..+16, cols 64c..+64
    int e_last = -1;

    for (int idx = idx0; idx < tot; idx += 128) {
        int e2, t2, cc;
        if (idx < n0)                { e2 = xcd;      t2 = idx;                cc = c0; }
        else if (idx < n0 + n1)      { e2 = xcd + 8;  t2 = idx - n0;           cc = c1; }
        else if (idx < n0 + n1 + n2) { e2 = xcd + 16; t2 = idx - n0 - n1;      cc = c2; }
        else                         { e2 = xcd + 24; t2 = idx - n0 - n1 - n2; cc = c3; }
        int rows = cc - t2 * 32; if (rows > 32) rows = 32;

        __syncthreads();                            // prev iter's readers done

        if (e2 != e_last) {
            // exclusive prefix scan of blk_cnt[e2][0..NRB) into s_pref
            int4v v = *(const int4v*)&blk_cnt[(size_t)e2 * NRB + tid * 4];
            int lsum = v[0] + v[1] + v[2] + v[3];
            int incl = lsum;
#pragma unroll
            for (int off = 1; off < 64; off <<= 1) {
                int t3 = __shfl_up(incl, off);
                if (lane >= off) incl += t3;
            }
            if (lane == 63) s_red[0][wv] = incl;
            __syncthreads();
            int woff = 0;
#pragma unroll
            for (int w2 = 0; w2 < 4; ++w2) if (w2 < wv) woff += s_red[0][w2];
            int excl = woff + incl - lsum;
            s_pref[tid * 4 + 0] = excl;
            s_pref[tid * 4 + 1] = excl + v[0];
            s_pref[tid * 4 + 2] = excl + v[0] + v[1];
            s_pref[tid * 4 + 3] = excl + v[0] + v[1] + v[2];
            if (tid == 255) s_pref[NRB] = excl + lsum;
            e_last = e2;
            __syncthreads();
        }

        // gather this tile's 32 entries via binary search on s_pref
        if (tid < 32) {
            int row = t2 * 32 + tid;
            bool val = tid < rows;
            int rr = val ? row : 0;
            int lo = 0, hi = NRB;
            while (hi - lo > 1) { int mid = (lo + hi) >> 1; if (s_pref[mid] <= rr) lo = mid; else hi = mid; }
            int sub = rr - s_pref[lo];
            s_ent[tid]  = tok_list[((size_t)e2 * NRB + lo) * 4 + sub];
            s_gate[tid] = val ? gate_list[((size_t)e2 * NRB + lo) * 4 + sub] : 0.0f;
        }
        __syncthreads();

        const u16* w1f = wf1 + (size_t)e2 * (128 * 512);
        const u16* w2f = wf2 + (size_t)e2 * (128 * 512);
        const u16* a0 = xbf + (size_t)(s_ent[16 * r + m] & 0xFFFF) * DM + q * 8;

        // GEMM1: k-steps in pairs, double-buffered
        short8 ab[2][2];
        short8 bb[2][2][4];
#pragma unroll
        for (int kk = 0; kk < 2; ++kk) {
            ab[0][kk] = *(const short8*)(a0 + 32 * kk);
            const u16* bp = w1f + (size_t)kk * 4096 + (size_t)(4 * c) * 512 + lane * 8;
#pragma unroll
            for (int n = 0; n < 4; ++n) bb[0][kk][n] = *(const short8*)(bp + n * 512);
        }
        f32x4 acc[4];
#pragma unroll
        for (int n = 0; n < 4; ++n) acc[n] = (f32x4){0.f, 0.f, 0.f, 0.f};

#pragma unroll
        for (int kp = 0; kp < 8; ++kp) {
            int cur = kp & 1, nxt = cur ^ 1;
            if (kp < 7) {
                int ks0 = 2 * (kp + 1);
#pragma unroll
                for (int kk = 0; kk < 2; ++kk) {
                    ab[nxt][kk] = *(const short8*)(a0 + 32 * (ks0 + kk));
                    const u16* bp = w1f + (size_t)(ks0 + kk) * 4096 + (size_t)(4 * c) * 512 + lane * 8;
#pragma unroll
                    for (int n = 0; n < 4; ++n) bb[nxt][kk][n] = *(const short8*)(bp + n * 512);
                }
            }
#pragma unroll
            for (int kk = 0; kk < 2; ++kk)
#pragma unroll
                for (int n = 0; n < 4; ++n)
                    acc[n] = __builtin_amdgcn_mfma_f32_16x16x32_bf16(ab[cur][kk],
                                                                     bb[cur][kk][n],
                                                                     acc[n], 0, 0, 0);
        }

        // relu * gate -> Hm
        {
            int rb = 16 * r + q * 4;
#pragma unroll
            for (int n = 0; n < 4; ++n)
#pragma unroll
                for (int rr2 = 0; rr2 < 4; ++rr2)
                    Hm[rb + rr2][64 * c + 16 * n + m] =
                        f2bf(fmaxf(acc[n][rr2], 0.f) * s_gate[rb + rr2]);
        }

        // GEMM2: wave owns cols [128*wv, +128); w2 frags double-buffered per k-slice
        short8 cb[2][8];
        {
            const u16* bp = w2f + (size_t)(wv * 8) * 512 + lane * 8;
#pragma unroll
            for (int n = 0; n < 8; ++n) cb[0][n] = *(const short8*)(bp + n * 512);
        }
        __syncthreads();                            // Hm ready

        f32x4 acc2[2][8];
#pragma unroll
        for (int i = 0; i < 2; ++i)
#pragma unroll
            for (int n = 0; n < 8; ++n) acc2[i][n] = (f32x4){0.f, 0.f, 0.f, 0.f};
#pragma unroll
        for (int ks = 0; ks < 4; ++ks) {
            int cur = ks & 1, nxt = cur ^ 1;
            if (ks < 3) {
                const u16* bp = w2f + (size_t)((ks + 1) * 32 + wv * 8) * 512 + lane * 8;
#pragma unroll
                for (int n = 0; n < 8; ++n) cb[nxt][n] = *(const short8*)(bp + n * 512);
            }
            short8 h0 = *(const short8*)&Hm[m][32 * ks + q * 8];
            short8 h1 = *(const short8*)&Hm[16 + m][32 * ks + q * 8];
#pragma unroll
            for (int n = 0; n < 8; ++n) {
                acc2[0][n] = __builtin_amdgcn_mfma_f32_16x16x32_bf16(h0, cb[cur][n], acc2[0][n], 0, 0, 0);
                acc2[1][n] = __builtin_amdgcn_mfma_f32_16x16x32_bf16(h1, cb[cur][n], acc2[1][n], 0, 0, 0);
            }
        }

        // C-layout -> LDS transpose (each wave writes its 128-col stripe)
#pragma unroll
        for (int i = 0; i < 2; ++i) {
            int rb = 16 * i + q * 4;
#pragma unroll
            for (int n = 0; n < 8; ++n)
#pragma unroll
                for (int rr2 = 0; rr2 < 4; ++rr2)
                    Ct[rb + rr2][128 * wv + 16 * n + m] = f2bf(acc2[i][n][rr2]);
        }
        __syncthreads();                            // Ct complete
        // contiguous row stores
#pragma unroll
        for (int rep = 0; rep < 8; ++rep) {
            int rl = rep * 4 + wv;                  // 0..31
            u16x8 v = *(const u16x8*)&Ct[rl][lane * 8];
            if (rl < rows) {
                int en = s_ent[rl];
                int tk = en & 0xFFFF, sl2 = en >> 16;
                if (use_part) {
                    *(u16x8*)(part + ((size_t)sl2 * NTOK + tk) * DM + lane * 8) = v;
                } else {
                    float* op = out + (size_t)tk * DM + lane * 8;
#pragma unroll
                    for (int j = 0; j < 8; ++j) atomicAdd(&op[j], bf2f(v[j]));
                }
            }
        }
    }
}

// ---------------- combine: out[t][c] = sum_k part[k][t][c] (verbatim R4) ----------------
__global__ __launch_bounds__(256) void combine_kernel(const u16* __restrict__ part,
                                                      float* __restrict__ out) {
    size_t off = ((size_t)blockIdx.x * 256 + threadIdx.x) * 8;
    float s[8] = {0, 0, 0, 0, 0, 0, 0, 0};
#pragma unroll
    for (int k = 0; k < TK; ++k) {
        u16x8 p = *(const u16x8*)(part + (size_t)k * NTOK * DM + off);
#pragma unroll
        for (int j = 0; j < 8; ++j) s[j] += bf2f(p[j]);
    }
    *(f32x4*)(out + off)     = (f32x4){s[0], s[1], s[2], s[3]};
    *(f32x4*)(out + off + 4) = (f32x4){s[4], s[5], s[6], s[7]};
}

extern "C" void kernel_launch(void* const* d_in, const int* in_sizes, int n_in,
                              void* d_out, int out_size, void* d_ws, size_t ws_size,
                              hipStream_t stream) {
    (void)in_sizes; (void)n_in; (void)out_size;
    const float* x   = (const float*)d_in[0];   // [N, D]
    const float* sel = (const float*)d_in[1];   // [E, D]
    const float* w1  = (const float*)d_in[2];   // [E, D, H]
    const float* w2  = (const float*)d_in[3];   // [E, H, D]
    float* out = (float*)d_out;                 // [N, D]

    char* ws = (char*)d_ws;
    int*   blk_cnt   = (int*)(ws);                                   // 128 KB
    int*   tok_list  = (int*)(ws + (size_t)NE * NRB * 4);            // 512 KB
    float* gate_list = (float*)(ws + (size_t)NE * NRB * 4 * 5);      // 512 KB
    u16*   xbf  = (u16*)(ws + (size_t)NE * NRB * 4 * 9);             // 4 MB
    u16*   wf1  = xbf + (size_t)NTOK * DM;                           // 4 MB
    u16*   wf2  = wf1 + (size_t)NE * HD * DM;                        // 4 MB
    u16*   part = wf2 + (size_t)NE * HD * DM;                        // 16.8 MB

    size_t need = (size_t)NE * NRB * 4 * 9 + (size_t)NTOK * DM * 2
                + 2 * (size_t)NE * HD * DM * 2 + (size_t)TK * NTOK * DM * 2;
    int use_part = (ws_size >= need) ? 1 : 0;

    if (!use_part)
        hipMemsetAsync(d_out, 0, (size_t)NTOK * DM * sizeof(float), stream);

    // blocks [0,1024) router; [1024,2048) swizzle. No memset node.
    prep_kernel<<<2048, 256, 0, stream>>>(x, sel, w1, w2, blk_cnt, tok_list,
                                          gate_list, xbf, wf1, wf2);
    // 8 XCD groups x 128 blocks, internal tile loop (verbatim R4)
    moe_mlp_kernel<<<1024, 256, 0, stream>>>(xbf, wf1, wf2, blk_cnt, tok_list,
                                             gate_list, part, out, use_part);
    if (use_part)
        combine_kernel<<<NTOK * DM / 8 / 256, 256, 0, stream>>>(part, out);
}